// Round 6
// baseline (1014.441 us; speedup 1.0000x reference)
//
#include <hip/hip_runtime.h>
#include <hip/hip_bf16.h>

// GraphUpsampler: N=4096 -> M=8192 dense GCN, 3 iters, out = sigmoid(Xu@Xu.T) f32 [8192,8192].
// R11: dispatch-graph diet (33 -> 23 launches).
//   - agg_full: conv aggregation as ONE kernel: M-tile 32, grid 256, K=8192 serial (no
//     split-K), 5-buf depth-4 counted-vmcnt pipeline (5 gld16/thread/stage -> 20/15/10/5/0),
//     T2-swizzled LDS, FUSED mode-1 epilogue (relu(dinv*s+bias) -> bf16 Xu direct).
//     Removes 6 reduce64 launches + 200MB accb round-trip per run.
//   - yz widened to 128 blocks (64 rows each) for occupancy.
//   Rebuilds (triangular), casts, upsample path unchanged from R10.

#define N_NODES 4096
#define M_NODES 8192
#define DIM 128
#define SLICE_ELEMS ((size_t)M_NODES * DIM)

typedef __attribute__((ext_vector_type(4))) float f32x4;
typedef __attribute__((ext_vector_type(8))) short bf16x8;

__device__ __forceinline__ unsigned short f2bf(float f) {
  union { float f; unsigned u; } v; v.f = f;
  unsigned r = v.u + 0x7fffu + ((v.u >> 16) & 1u);
  return (unsigned short)(r >> 16);
}

__device__ __forceinline__ void gld16(unsigned short* lds, const unsigned short* g) {
  __builtin_amdgcn_global_load_lds(
      (const __attribute__((address_space(1))) unsigned int*)g,
      (__attribute__((address_space(3))) unsigned int*)lds, 16, 0, 0);
}

__device__ __forceinline__ float sigmoidf_(float x) { return 1.0f / (1.0f + __expf(-x)); }

// ---------------- cast / init kernels ----------------

__global__ void cast_x_kernel(const float* __restrict__ X, unsigned short* __restrict__ Xu,
                              unsigned short* __restrict__ XT,
                              float* __restrict__ colsumA) {
  int idx = blockIdx.x * 256 + threadIdx.x;          // N*DIM
  if (idx < N_NODES) colsumA[idx] = 0.f;             // folded memset (before cast_a)
  int i = idx >> 7, c = idx & 127;
  unsigned short b = f2bf(X[idx]);
  Xu[idx] = b;
  XT[(size_t)c * N_NODES + i] = b;                   // X^T [128][4096]
}

// both 128x128 conv weights -> W^T [out][in] bf16, one launch
__global__ void cast_wt2_kernel(const float* __restrict__ W1, const float* __restrict__ W2,
                                unsigned short* __restrict__ WT1,
                                unsigned short* __restrict__ WT2) {
  int idx = blockIdx.x * 256 + threadIdx.x;          // 2*128*128
  const float* W = idx < 16384 ? W1 : W2;
  unsigned short* WT = idx < 16384 ? WT1 : WT2;
  int j = idx & 16383;
  int k = j >> 7, c = j & 127;
  WT[c * DIM + k] = f2bf(W[j]);
}

// A f32 -> 3 blocks of stage-tiled Adj ([[A,A],[A,.]], A symmetric) + colsum(A)
__global__ void cast_a_kernel(const float* __restrict__ A, unsigned short* __restrict__ Adj,
                              float* __restrict__ colsumA) {
  int c = blockIdx.x * 256 + threadIdx.x;            // grid.x = 16
  int r0 = blockIdx.y * 128;
  int tm = r0 >> 7;
  int kc = c >> 10, st = (c & 1023) >> 5, e = c & 31;
  size_t a1 = ((size_t)(tm)      * 8 + kc)     * 131072 + (size_t)st * 4096 + e;  // (r,c)
  size_t a2 = ((size_t)(tm)      * 8 + 4 + kc) * 131072 + (size_t)st * 4096 + e;  // (r,4096+c)
  size_t a3 = ((size_t)(tm + 32) * 8 + kc)     * 131072 + (size_t)st * 4096 + e;  // (4096+r,c)
  float s = 0.f;
  for (int r = 0; r < 128; ++r) {
    float a = A[(size_t)(r0 + r) * N_NODES + c];
    unsigned short b = f2bf(a);
    Adj[a1 + r * 32] = b; Adj[a2 + r * 32] = b; Adj[a3 + r * 32] = b;
    s += a;
  }
  atomicAdd(&colsumA[c], s);
}

__global__ void init_deg_kernel(const float* __restrict__ colsumA, float* __restrict__ deg) {
  int i = blockIdx.x * 256 + threadIdx.x;            // 8192
  deg[i] = (i < N_NODES) ? 2.0f * colsumA[i] : colsumA[i - N_NODES];
}

// ---------------- conv aggregation: M-tile 32, FULL K=8192, fused epilogue ----------------
// Xu[r0..r0+32][:] = relu(dinv(deg) * (Adj(stage-tiled) @ ZT^T) + bias_col), bf16.
// Grid 256 (1 block/CU). K-step 64 (2 sub-stages of the 32-wide tiled layout).
// Per stage/thread exactly 5 gld16 (A 1 + B 4) -> counted vmcnt 20/15/10/5/0, 5 bufs, depth-4.
// LDS per buf: A [32 r][64 k] 4KB + B [128 n][64 k] 16KB, phys chunk = c ^ (row&7) swizzle
// (write via pre-swizzled source, read via lane XOR key -> conflict-free b128).

__global__ __launch_bounds__(256, 1)
void agg_full(const unsigned short* __restrict__ At,
              const unsigned short* __restrict__ BT, long ldb,
              unsigned short* __restrict__ Xout,
              const float* __restrict__ bias_col,
              const float* __restrict__ deg) {
  __shared__ __align__(16) unsigned short smem[51200];   // 5 x (2048 A + 8192 B) elems
  const int t = threadIdx.x, w = t >> 6, lane = t & 63;
  const int q = lane >> 4, l15 = lane & 15;
  const int ms = w & 1, nh = w >> 1;                 // m-sub strip / n-half
  const int r0 = blockIdx.x * 32;
  const int tm = blockIdx.x >> 2;                    // 128-row tile
  const int rr = (blockIdx.x & 3) * 32 + (t >> 3);   // row within tile for A staging
  // A staging source swizzle: dest (row=t>>3, phys=t&7) <- logical chunk cA
  const int cA = (t & 7) ^ ((t >> 3) & 7);
  const int sgAdd = cA >> 2;                         // which 32-wide sub-stage
  const int koffA = (cA & 3) * 8;

  auto STAGE = [&](int s, int b) {
    unsigned short* la = smem + b * 10240;
    unsigned short* lb = la + 2048;
    int sg = 2 * s + sgAdd;
    gld16(&la[t * 8],
          &At[((size_t)tm * 8 + (sg >> 5)) * 131072 + (size_t)(sg & 31) * 4096 + rr * 32 + koffA]);
#pragma unroll
    for (int j = 0; j < 4; ++j) {
      int ch = j * 256 + t;
      int n = ch >> 3, phys = ch & 7;
      int c = phys ^ (n & 7);
      gld16(&lb[ch * 8], &BT[(size_t)n * ldb + (size_t)s * 64 + c * 8]);
    }
  };

  f32x4 acc[4];
#pragma unroll
  for (int b = 0; b < 4; ++b) acc[b] = (f32x4)0.f;

  STAGE(0, 0); STAGE(1, 1); STAGE(2, 2); STAGE(3, 3);

  int cur = 0, nxt = 4;
  for (int s = 0; s < 128; ++s) {
    if (s + 4 < 128) {
      STAGE(s + 4, nxt);
      nxt = (nxt == 4) ? 0 : nxt + 1;
      asm volatile("s_waitcnt vmcnt(20)" ::: "memory");  // stage s's 5 loads complete
    } else if (s + 3 < 128) {
      asm volatile("s_waitcnt vmcnt(15)" ::: "memory");
    } else if (s + 2 < 128) {
      asm volatile("s_waitcnt vmcnt(10)" ::: "memory");
    } else if (s + 1 < 128) {
      asm volatile("s_waitcnt vmcnt(5)" ::: "memory");
    } else {
      asm volatile("s_waitcnt vmcnt(0)" ::: "memory");
    }
    __builtin_amdgcn_s_barrier();
    __builtin_amdgcn_sched_barrier(0);

    const unsigned short* la = smem + cur * 10240;
    const unsigned short* lb = la + 2048;
    const int xk = (l15 & 7);                        // read-side XOR key
#pragma unroll
    for (int ks = 0; ks < 2; ++ks) {
      bf16x8 a0 = *(const bf16x8*)&la[(ms * 16 + l15) * 64 + ((ks * 4 + q) ^ xk) * 8];
#pragma unroll
      for (int nt = 0; nt < 4; ++nt) {
        int n = nh * 64 + nt * 16 + l15;
        bf16x8 b = *(const bf16x8*)&lb[n * 64 + ((ks * 4 + q) ^ xk) * 8];
        acc[nt] = __builtin_amdgcn_mfma_f32_16x16x32_bf16(a0, b, acc[nt], 0, 0, 0);
      }
    }
    __builtin_amdgcn_sched_barrier(0);
    __builtin_amdgcn_s_barrier();                    // buf cur free for reuse
    __builtin_amdgcn_sched_barrier(0);
    cur = (cur == 4) ? 0 : cur + 1;
  }

  // fused epilogue: relu(dinv*s + bias_col) -> bf16 row-major
#pragma unroll
  for (int i = 0; i < 4; ++i) {
    int row = r0 + ms * 16 + q * 4 + i;
    float d = deg[row];
    float dv = d > 0.f ? rsqrtf(d) : 0.f;
#pragma unroll
    for (int nt = 0; nt < 4; ++nt) {
      int col = nh * 64 + nt * 16 + l15;
      Xout[(size_t)row * DIM + col] = f2bf(fmaxf(dv * acc[nt][i] + bias_col[col], 0.f));
    }
  }
}

// ---------------- upsample GEMM reading W_up f32 directly ----------------
// out_partial[by] = f2bf(W_up)[64 rows x 512 k] @ X (XT [128 d][4096 k]).

__global__ __launch_bounds__(256)
void up_agg_f32(const float* __restrict__ Wup, const unsigned short* __restrict__ BT,
                float* __restrict__ accBase) {
  __shared__ __align__(16) unsigned short smem[6144];    // A 4KB + B 8KB
  unsigned short* la = smem;
  unsigned short* lb = smem + 2048;
  const int t = threadIdx.x, w = t >> 6, lane = t & 63;
  const int q = lane >> 4, l15 = lane & 15;
  const int r0 = blockIdx.x * 64;                    // output rows
  const int k0 = blockIdx.y * 512;                   // k split
  const int arow = t >> 2, achk = t & 3;

  f32x4 acc[8];
#pragma unroll
  for (int b = 0; b < 8; ++b) acc[b] = (f32x4)0.f;

  for (int s = 0; s < 16; ++s) {
    int kb = k0 + s * 32;
    __syncthreads();
    gld16(&lb[t * 8],        &BT[(size_t)arow * N_NODES + kb + achk * 8]);
    gld16(&lb[2048 + t * 8], &BT[(size_t)(64 + arow) * N_NODES + kb + achk * 8]);
    const float* ap = &Wup[(size_t)(r0 + (t >> 2)) * N_NODES + kb + (t & 3) * 8];
    float4 v0 = *(const float4*)ap;
    float4 v1 = *(const float4*)(ap + 4);
    ushort4 o0, o1;
    o0.x = f2bf(v0.x); o0.y = f2bf(v0.y); o0.z = f2bf(v0.z); o0.w = f2bf(v0.w);
    o1.x = f2bf(v1.x); o1.y = f2bf(v1.y); o1.z = f2bf(v1.z); o1.w = f2bf(v1.w);
    *(ushort4*)&la[t * 8] = o0;
    *(ushort4*)&la[t * 8 + 4] = o1;
    __syncthreads();                                 // drains vm+lgkm: tiles visible

    bf16x8 a0 = *(const bf16x8*)&la[(w * 16 + l15) * 32 + q * 8];
#pragma unroll
    for (int nt = 0; nt < 8; ++nt) {
      bf16x8 b = *(const bf16x8*)&lb[(nt * 16 + l15) * 32 + q * 8];
      acc[nt] = __builtin_amdgcn_mfma_f32_16x16x32_bf16(a0, b, acc[nt], 0, 0, 0);
    }
  }
  float* ct = accBase + (size_t)blockIdx.y * SLICE_ELEMS + (size_t)blockIdx.x * 8192;
#pragma unroll
  for (int nt = 0; nt < 8; ++nt)
    *(f32x4*)&ct[((w * 8 + nt) * 256) + (q * 16 + l15) * 4] = acc[nt];
}

// sum packed (M64-tile) partials + epilogue -> bf16 row-major (upsample only, mode 0)
__global__ void reduce64_kernel(const float* __restrict__ acc,
                                unsigned short* __restrict__ dst,
                                const float* __restrict__ bias_row, int nSlices) {
  int p = blockIdx.x * 256 + threadIdx.x;
  float s = 0.f;
  for (int sp = 0; sp < nSlices; ++sp) s += acc[(size_t)sp * SLICE_ELEMS + p];
  int tile = p >> 13, r = p & 8191;
  int grp = r >> 8;                                  // w*8+nt
  int w = grp >> 3, nt = grp & 7;
  int r2 = r & 255;
  int i = r2 & 3, ql = r2 >> 2;
  int row = tile * 64 + w * 16 + (ql >> 4) * 4 + i;
  int col = nt * 16 + (ql & 15);
  dst[(size_t)row * DIM + col] = f2bf(s + bias_row[row]);
}

// ---------------- TRIANGULAR rebuild: S = sigmoid(XA @ XB^T), K=128, S symmetric ----------
// (unchanged from R10; staging T2-swizzled; bitwise-identical mirrored tiles)

template <int MODE>
__global__ __launch_bounds__(256)
void rebuild_kernel(const unsigned short* __restrict__ XA,
                    const unsigned short* __restrict__ XB,
                    void* __restrict__ out, long p1 /*MODE0:row0, MODE1:ldo*/,
                    long col0, float* __restrict__ deg, int nB) {
  __shared__ __align__(16) unsigned short smem[34816];   // 69.6KB: staging 64KB / lC+lCt
  __shared__ float lcol[128];
  __shared__ float lrow[128];
  unsigned short* lA = smem;
  unsigned short* lB = smem + 16384;
  const int t = threadIdx.x, w = t >> 6, lane = t & 63;
  const int q = lane >> 4, l15 = lane & 15;
  const int sx = (l15 >> 1) & 3;                     // read-side swizzle key

  int rem = blockIdx.x, bi = 0;
  while (rem >= nB - bi) { rem -= nB - bi; ++bi; }
  const int bj = bi + rem;
  const int i0 = bi * 128, j0 = bj * 128;
  const bool offdiag = (bi != bj);

  const int srow = t >> 2;
  const int xchk = (t & 3) ^ ((t >> 3) & 3);         // source chunk (pre-swizzled)
#pragma unroll
  for (int kk = 0; kk < 4; ++kk)
#pragma unroll
    for (int h = 0; h < 2; ++h) {
      gld16(&lA[kk * 4096 + h * 2048 + t * 8],
            &XA[(size_t)(i0 + h * 64 + srow) * DIM + kk * 32 + xchk * 8]);
      gld16(&lB[kk * 4096 + h * 2048 + t * 8],
            &XB[(size_t)(j0 + h * 64 + srow) * DIM + kk * 32 + xchk * 8]);
    }
  if (MODE == 0 && t < 128) { lcol[t] = 0.f; lrow[t] = 0.f; }
  __syncthreads();

  f32x4 acc[2][8];
#pragma unroll
  for (int a = 0; a < 2; ++a)
#pragma unroll
    for (int b = 0; b < 8; ++b) acc[a][b] = (f32x4)0.f;

#pragma unroll
  for (int kk = 0; kk < 4; ++kk) {
    bf16x8 a0 = *(const bf16x8*)&lA[kk * 4096 + (w * 32 + l15) * 32 + ((q ^ sx)) * 8];
    bf16x8 a1 = *(const bf16x8*)&lA[kk * 4096 + (w * 32 + 16 + l15) * 32 + ((q ^ sx)) * 8];
#pragma unroll
    for (int nt = 0; nt < 8; ++nt) {
      bf16x8 b = *(const bf16x8*)&lB[kk * 4096 + (nt * 16 + l15) * 32 + ((q ^ sx)) * 8];
      acc[0][nt] = __builtin_amdgcn_mfma_f32_16x16x32_bf16(a0, b, acc[0][nt], 0, 0, 0);
      acc[1][nt] = __builtin_amdgcn_mfma_f32_16x16x32_bf16(a1, b, acc[1][nt], 0, 0, 0);
    }
  }
  __syncthreads();   // staging reads done; smem reusable

  if (MODE == 0) {
    unsigned short* lC  = smem;          // [128][136] bf16
    unsigned short* lCt = smem + 17408;  // [128][136] bf16 (transposed tile)
    float rs[2][4] = {{0.f, 0.f, 0.f, 0.f}, {0.f, 0.f, 0.f, 0.f}};
#pragma unroll
    for (int mt = 0; mt < 2; ++mt)
#pragma unroll
      for (int nt = 0; nt < 8; ++nt) {
        float cs = 0.f;
#pragma unroll
        for (int i = 0; i < 4; ++i) {
          float sv = sigmoidf_(acc[mt][nt][i]);
          cs += sv;
          unsigned short hb = f2bf(sv);
          int row = w * 32 + mt * 16 + q * 4 + i, colL = nt * 16 + l15;
          lC[row * 136 + colL] = hb;
          if (offdiag) { lCt[colL * 136 + row] = hb; rs[mt][i] += sv; }
        }
        cs += __shfl_xor(cs, 16);
        cs += __shfl_xor(cs, 32);
        if (lane < 16) atomicAdd(&lcol[nt * 16 + lane], cs);
      }
    if (offdiag) {
#pragma unroll
      for (int mt = 0; mt < 2; ++mt)
#pragma unroll
        for (int i = 0; i < 4; ++i) {
          float v = rs[mt][i];
          v += __shfl_xor(v, 1); v += __shfl_xor(v, 2);
          v += __shfl_xor(v, 4); v += __shfl_xor(v, 8);
          if (l15 == 0) atomicAdd(&lrow[w * 32 + mt * 16 + q * 4 + i], v);
        }
    }
    __syncthreads();
    unsigned short* og = (unsigned short*)out;
    {
      const long rowbase = p1 + i0, colbase = col0 + j0;
      const size_t tb = ((size_t)(rowbase >> 7) * 8 + (colbase >> 10)) * 131072;
      const int stb = (int)((colbase & 1023) >> 5);
#pragma unroll
      for (int cc = 0; cc < 8; ++cc) {
        int ch = t + cc * 256;
        int row = ch >> 4, c16 = ch & 15;
        *(bf16x8*)&og[tb + (size_t)(stb + (c16 >> 2)) * 4096 + row * 32 + (c16 & 3) * 8] =
            *(const bf16x8*)&lC[row * 136 + c16 * 8];
      }
    }
    if (offdiag) {
      const long rowbase = p1 + j0, colbase = col0 + i0;
      const size_t tb = ((size_t)(rowbase >> 7) * 8 + (colbase >> 10)) * 131072;
      const int stb = (int)((colbase & 1023) >> 5);
#pragma unroll
      for (int cc = 0; cc < 8; ++cc) {
        int ch = t + cc * 256;
        int row = ch >> 4, c16 = ch & 15;
        *(bf16x8*)&og[tb + (size_t)(stb + (c16 >> 2)) * 4096 + row * 32 + (c16 & 3) * 8] =
            *(const bf16x8*)&lCt[row * 136 + c16 * 8];
      }
    }
    if (t < 128) atomicAdd(&deg[col0 + j0 + t], lcol[t]);
    if (offdiag && t < 128) atomicAdd(&deg[col0 + i0 + t], lrow[t]);
  } else {
    float* og = (float*)out;
    float* lCf = (float*)smem;                   // [64][132] f32, stride keeps 16B align
#pragma unroll
    for (int mt = 0; mt < 2; ++mt)
#pragma unroll
      for (int nt = 0; nt < 8; ++nt)
#pragma unroll
        for (int i = 0; i < 4; ++i) acc[mt][nt][i] = sigmoidf_(acc[mt][nt][i]);
#pragma unroll
    for (int h2 = 0; h2 < 2; ++h2) {
      __syncthreads();
      if ((w >> 1) == h2) {
#pragma unroll
        for (int mt = 0; mt < 2; ++mt)
#pragma unroll
          for (int nt = 0; nt < 8; ++nt)
#pragma unroll
            for (int i = 0; i < 4; ++i)
              lCf[((w & 1) * 32 + mt * 16 + q * 4 + i) * 132 + nt * 16 + l15] =
                  acc[mt][nt][i];
      }
      __syncthreads();
#pragma unroll
      for (int j = 0; j < 8; ++j) {
        int ch = t + j * 256;
        int r64 = ch >> 5, c4 = (ch & 31) * 4;
        *(f32x4*)&og[(size_t)(i0 + h2 * 64 + r64) * p1 + j0 + c4] =
            *(const f32x4*)&lCf[r64 * 132 + c4];
      }
    }
    if (offdiag) {
#pragma unroll
      for (int h2 = 0; h2 < 2; ++h2) {
        __syncthreads();
#pragma unroll
        for (int mt = 0; mt < 2; ++mt)
#pragma unroll
          for (int nt = 0; nt < 8; ++nt)
            if ((nt >> 2) == h2) {
#pragma unroll
              for (int i = 0; i < 4; ++i)
                lCf[((nt & 3) * 16 + l15) * 132 + (w * 32 + mt * 16 + q * 4 + i)] =
                    acc[mt][nt][i];
            }
        __syncthreads();
#pragma unroll
        for (int j = 0; j < 8; ++j) {
          int ch = t + j * 256;
          int r64 = ch >> 5, c4 = (ch & 31) * 4;
          *(f32x4*)&og[(size_t)(j0 + h2 * 64 + r64) * p1 + i0 + c4] =
              *(const f32x4*)&lCf[r64 * 132 + c4];
        }
      }
    }
  }
}

// ---------------- Z^T = (rsqrt(deg) ⊙ (Xu @ W)) transposed, [128][8192] ----------------
// R11: 128 blocks x 64 rows (was 64x128) for occupancy. T2-swizzled staging.
// zbuf (optional): zero next-gen deg buffer (folds a memset launch).

__global__ __launch_bounds__(256)
void yz_kernel(const unsigned short* __restrict__ Xu, const unsigned short* __restrict__ WT,
               const float* __restrict__ deg, unsigned short* __restrict__ ZT, int ldz,
               float* __restrict__ zbuf) {
  __shared__ __align__(16) unsigned short smem[24576];   // lA 64x128 16KB + lB 128x128 32KB
  unsigned short* lA = smem;                             // [64 r][16 chunk swz]
  unsigned short* lB = smem + 8192;                      // [128 r][16 chunk swz]
  const int t = threadIdx.x, w = t >> 6, lane = t & 63;
  const int q = lane >> 4, l15 = lane & 15;
  const int r0 = blockIdx.x * 64;
  if (zbuf && t < 64) zbuf[blockIdx.x * 64 + t] = 0.f;
  // staging: phys chunk = c ^ (row&7); dest linear
#pragma unroll
  for (int j = 0; j < 4; ++j) {
    int ch = j * 256 + t;
    int row = ch >> 4, phys = ch & 15;
    int c = phys ^ (row & 7);
    gld16(&lA[ch * 8], &Xu[(size_t)(r0 + row) * DIM + c * 8]);
  }
#pragma unroll
  for (int j = 0; j < 8; ++j) {
    int ch = j * 256 + t;
    int row = ch >> 4, phys = ch & 15;
    int c = phys ^ (row & 7);
    gld16(&lB[ch * 8], &WT[(size_t)row * DIM + c * 8]);
  }
  __syncthreads();

  f32x4 acc[8];
#pragma unroll
  for (int b = 0; b < 8; ++b) acc[b] = (f32x4)0.f;

  const int xk = l15 & 7;
#pragma unroll
  for (int kk = 0; kk < 4; ++kk) {
    bf16x8 a0 = *(const bf16x8*)&lA[(w * 16 + l15) * 128 + ((kk * 4 + q) ^ xk) * 8];
#pragma unroll
    for (int nt = 0; nt < 8; ++nt) {
      bf16x8 b = *(const bf16x8*)&lB[(nt * 16 + l15) * 128 + ((kk * 4 + q) ^ xk) * 8];
      acc[nt] = __builtin_amdgcn_mfma_f32_16x16x32_bf16(a0, b, acc[nt], 0, 0, 0);
    }
  }
  __syncthreads();
  unsigned short* lT = smem;   // [c 128][r 72] bf16 (stride 72 keeps 16B align)
#pragma unroll
  for (int i = 0; i < 4; ++i) {
    int r = w * 16 + q * 4 + i;
    float d = deg[r0 + r];
    float dv = d > 0.f ? rsqrtf(d) : 0.f;
#pragma unroll
    for (int nt = 0; nt < 8; ++nt)
      lT[(nt * 16 + l15) * 72 + r] = f2bf(dv * acc[nt][i]);
  }
  __syncthreads();
#pragma unroll
  for (int j = 0; j < 4; ++j) {
    int ch = t + j * 256;                            // 1024 bf16x8 chunks
    int c = ch >> 3, chunk = ch & 7;
    *(bf16x8*)&ZT[(size_t)c * ldz + r0 + chunk * 8] = *(const bf16x8*)&lT[c * 72 + chunk * 8];
  }
}

// ---------------- driver ----------------

extern "C" void kernel_launch(void* const* d_in, const int* in_sizes, int n_in,
                              void* d_out, int out_size, void* d_ws, size_t ws_size,
                              hipStream_t stream) {
  (void)in_sizes; (void)n_in; (void)out_size;
  const float* X   = (const float*)d_in[0];
  const float* A   = (const float*)d_in[1];
  const float* Wup = (const float*)d_in[2];
  const float* bup = (const float*)d_in[3];
  const float* W1  = (const float*)d_in[4];
  const float* b1  = (const float*)d_in[5];
  const float* W2  = (const float*)d_in[6];
  const float* b2  = (const float*)d_in[7];

  const size_t ADJ_BYTES = (size_t)M_NODES * M_NODES * 2;
  char* ws = (char*)d_ws;
  size_t off = 0;
  auto alloc = [&](size_t bytes) {
    char* p = ws + off;
    off += (bytes + 255) & ~(size_t)255;
    return p;
  };
  float*          accb    = (float*)alloc(8 * SLICE_ELEMS * 4);                  // 33.5 MB
  unsigned short* Xu      = (unsigned short*)alloc((size_t)M_NODES * DIM * 2);
  unsigned short* ZT      = (unsigned short*)alloc((size_t)DIM * M_NODES * 2);
  unsigned short* XT      = (unsigned short*)alloc((size_t)DIM * N_NODES * 2);
  unsigned short* W1T     = (unsigned short*)alloc(DIM * DIM * 2);
  unsigned short* W2T     = (unsigned short*)alloc(DIM * DIM * 2);
  float*          colsumA = (float*)alloc(N_NODES * 4);
  float*          degA    = (float*)alloc(M_NODES * 4);
  float*          degB    = (float*)alloc(M_NODES * 4);

  unsigned short* Adj;
  if (ws_size >= off + ADJ_BYTES) Adj = (unsigned short*)(ws + off);
  else                            Adj = (unsigned short*)d_out;  // Adj dead before final write

  unsigned short* XuNew = Xu + (size_t)N_NODES * DIM;

  cast_x_kernel<<<N_NODES * DIM / 256, 256, 0, stream>>>(X, Xu, XT, colsumA);
  cast_wt2_kernel<<<128, 256, 0, stream>>>(W1, W2, W1T, W2T);

  // new = W_up @ X (+ b_up): K=4096, direct f32 A-read, 8 splits x 16 stages
  up_agg_f32<<<dim3(N_NODES / 64, 8), 256, 0, stream>>>(Wup, XT, accb);
  reduce64_kernel<<<N_NODES * DIM / 256, 256, 0, stream>>>(accb, XuNew, bup, 8);

  // Adj0 blocks [[A,A],[A,.]] tiled + colsum; deg; S0 = sigmoid(new@new^T) into (4096+,4096+)
  cast_a_kernel<<<dim3(N_NODES / 256, N_NODES / 128), 256, 0, stream>>>(A, Adj, colsumA);
  init_deg_kernel<<<M_NODES / 256, 256, 0, stream>>>(colsumA, degA);
  rebuild_kernel<0><<<32 * 33 / 2, 256, 0, stream>>>(
      XuNew, XuNew, Adj, N_NODES, N_NODES, degA, 32);

  float* degCur = degA;   // deg for conv1 (prev generation's mid-loop Adj)
  float* degMid = degB;   // deg for this generation's mid-loop Adj
  for (int it = 0; it < 3; ++it) {
    // conv1 (Adj = prev mid-loop matrix; iter0: Adj0). yz also zeroes degMid.
    yz_kernel<<<M_NODES / 64, 256, 0, stream>>>(Xu, W1T, degCur, ZT, M_NODES, degMid);
    agg_full<<<M_NODES / 32, 256, 0, stream>>>(Adj, ZT, M_NODES, Xu, b1, degCur);
    // mid-loop Adj rebuild (triangular) + deg into degMid
    rebuild_kernel<0><<<64 * 65 / 2, 256, 0, stream>>>(
        Xu, Xu, Adj, 0, 0, degMid, 64);
    // conv2 (Adj = mid-loop matrix)
    yz_kernel<<<M_NODES / 64, 256, 0, stream>>>(Xu, W2T, degMid, ZT, M_NODES, nullptr);
    agg_full<<<M_NODES / 32, 256, 0, stream>>>(Adj, ZT, M_NODES, Xu, b2, degMid);
    if (it == 2)
      rebuild_kernel<1><<<64 * 65 / 2, 256, 0, stream>>>(
          Xu, Xu, d_out, M_NODES, 0, nullptr, 64);
    float* tmp = degCur; degCur = degMid; degMid = tmp;
  }
}

// Round 7
// 901.677 us; speedup vs baseline: 1.1251x; 1.1251x over previous
//
#include <hip/hip_runtime.h>
#include <hip/hip_bf16.h>

// GraphUpsampler: N=4096 -> M=8192 dense GCN, 3 iters, out = sigmoid(Xu@Xu.T) f32 [8192,8192].
// R12: full revert to R10 (proven 908us; R11's 1-block/CU mega-kernel regressed) + ONE change:
//   agg64 wave remap 4x1 -> 2x2. Each wave now owns 32 rows x 64 cols (2 A-frags + 4 B-frags
//   = 6 ds_read_b128/stage vs 9; B-fragment redundancy across waves halved) at identical MFMA
//   count, staging, and counted-vmcnt pipeline. Packed-C layout + reduce64 mode-1 decode
//   updated to match. All other kernels byte-identical to R10.

#define N_NODES 4096
#define M_NODES 8192
#define DIM 128
#define SLICE_ELEMS ((size_t)M_NODES * DIM)

typedef __attribute__((ext_vector_type(4))) float f32x4;
typedef __attribute__((ext_vector_type(8))) short bf16x8;

__device__ __forceinline__ unsigned short f2bf(float f) {
  union { float f; unsigned u; } v; v.f = f;
  unsigned r = v.u + 0x7fffu + ((v.u >> 16) & 1u);
  return (unsigned short)(r >> 16);
}

__device__ __forceinline__ void gld16(unsigned short* lds, const unsigned short* g) {
  __builtin_amdgcn_global_load_lds(
      (const __attribute__((address_space(1))) unsigned int*)g,
      (__attribute__((address_space(3))) unsigned int*)lds, 16, 0, 0);
}

__device__ __forceinline__ float sigmoidf_(float x) { return 1.0f / (1.0f + __expf(-x)); }

// ---------------- cast / init kernels ----------------

__global__ void cast_x_kernel(const float* __restrict__ X, unsigned short* __restrict__ Xu,
                              unsigned short* __restrict__ XT,
                              float* __restrict__ colsumA) {
  int idx = blockIdx.x * 256 + threadIdx.x;          // N*DIM
  if (idx < N_NODES) colsumA[idx] = 0.f;             // folded memset (before cast_a)
  int i = idx >> 7, c = idx & 127;
  unsigned short b = f2bf(X[idx]);
  Xu[idx] = b;
  XT[(size_t)c * N_NODES + i] = b;                   // X^T [128][4096]
}

// both 128x128 conv weights -> W^T [out][in] bf16, one launch
__global__ void cast_wt2_kernel(const float* __restrict__ W1, const float* __restrict__ W2,
                                unsigned short* __restrict__ WT1,
                                unsigned short* __restrict__ WT2) {
  int idx = blockIdx.x * 256 + threadIdx.x;          // 2*128*128
  const float* W = idx < 16384 ? W1 : W2;
  unsigned short* WT = idx < 16384 ? WT1 : WT2;
  int j = idx & 16383;
  int k = j >> 7, c = j & 127;
  WT[c * DIM + k] = f2bf(W[j]);
}

// A f32 -> 3 blocks of stage-tiled Adj ([[A,A],[A,.]], A symmetric) + colsum(A)
__global__ void cast_a_kernel(const float* __restrict__ A, unsigned short* __restrict__ Adj,
                              float* __restrict__ colsumA) {
  int c = blockIdx.x * 256 + threadIdx.x;            // grid.x = 16
  int r0 = blockIdx.y * 128;
  int tm = r0 >> 7;
  int kc = c >> 10, st = (c & 1023) >> 5, e = c & 31;
  size_t a1 = ((size_t)(tm)      * 8 + kc)     * 131072 + (size_t)st * 4096 + e;  // (r,c)
  size_t a2 = ((size_t)(tm)      * 8 + 4 + kc) * 131072 + (size_t)st * 4096 + e;  // (r,4096+c)
  size_t a3 = ((size_t)(tm + 32) * 8 + kc)     * 131072 + (size_t)st * 4096 + e;  // (4096+r,c)
  float s = 0.f;
  for (int r = 0; r < 128; ++r) {
    float a = A[(size_t)(r0 + r) * N_NODES + c];
    unsigned short b = f2bf(a);
    Adj[a1 + r * 32] = b; Adj[a2 + r * 32] = b; Adj[a3 + r * 32] = b;
    s += a;
  }
  atomicAdd(&colsumA[c], s);
}

__global__ void init_deg_kernel(const float* __restrict__ colsumA, float* __restrict__ deg) {
  int i = blockIdx.x * 256 + threadIdx.x;            // 8192
  deg[i] = (i < N_NODES) ? 2.0f * colsumA[i] : colsumA[i - N_NODES];
}

// ---------------- conv aggregation GEMM: M-tile 64, split-K 4, pipelined, T2-swizzled ----
// C_partial[by] = Adj(stage-tiled)[64 rows x 2048 k] @ Z (ZT [128 n][8192 k]).
// 3 gld16/thread/stage; triple-buffered; counted vmcnt 6/3/0.
// R12: 2x2 wave grid — wave (wm=w&1, wn=w>>1) owns rows wm*32..+32, cols wn*64..+64.
// Per stage/wave: 2 A + 4 B ds_read_b128 (was 1+8). Same 8 MFMA.

__global__ __launch_bounds__(256, 2)
void agg64_kernel(const unsigned short* __restrict__ At,
                  const unsigned short* __restrict__ BT, long ldb,
                  float* __restrict__ accBase, int kIters) {
  __shared__ __align__(16) unsigned short smem[18432];   // 3 bufs x (4KB A + 8KB B)
  const int t = threadIdx.x, w = t >> 6, lane = t & 63;
  const int q = lane >> 4, l15 = lane & 15;
  const int sx = (l15 >> 1) & 3;                     // read-side swizzle key
  const int wm = w & 1, wn = w >> 1;                 // 2x2 wave grid
  const int tm = blockIdx.x >> 1;                    // 128-row tile in stage-tiled layout
  const int h2048 = (blockIdx.x & 1) * 2048;         // which 64-row half (elem offset)
  const int sg0 = blockIdx.y * kIters;               // global stage index
  const int arow = t >> 2;
  const int xchk = (t & 3) ^ ((t >> 3) & 3);         // source chunk (pre-swizzled)

  auto STAGE = [&](int s, int b) {
    unsigned short* la = smem + b * 6144;
    unsigned short* lb = la + 2048;
    int sg = sg0 + s;
    size_t aaddr = ((size_t)tm * 8 + (sg >> 5)) * 131072 + (size_t)(sg & 31) * 4096 + h2048;
    gld16(&la[t * 8],        &At[aaddr + arow * 32 + xchk * 8]);
    gld16(&lb[t * 8],        &BT[(size_t)arow * ldb + (size_t)sg * 32 + xchk * 8]);
    gld16(&lb[2048 + t * 8], &BT[(size_t)(64 + arow) * ldb + (size_t)sg * 32 + xchk * 8]);
  };

  f32x4 acc[2][4];
#pragma unroll
  for (int a = 0; a < 2; ++a)
#pragma unroll
    for (int b = 0; b < 4; ++b) acc[a][b] = (f32x4)0.f;

  STAGE(0, 0);
  STAGE(1, 1);

  for (int s = 0; s < kIters; ++s) {
    if (s + 2 < kIters) {
      STAGE(s + 2, (s + 2) % 3);
      asm volatile("s_waitcnt vmcnt(6)" ::: "memory");   // stage s's 3 loads complete
    } else if (s + 1 < kIters) {
      asm volatile("s_waitcnt vmcnt(3)" ::: "memory");
    } else {
      asm volatile("s_waitcnt vmcnt(0)" ::: "memory");
    }
    __builtin_amdgcn_s_barrier();
    __builtin_amdgcn_sched_barrier(0);

    const unsigned short* la = smem + (s % 3) * 6144;
    const unsigned short* lb = la + 2048;
    bf16x8 a0 = *(const bf16x8*)&la[(wm * 32 + l15) * 32 + (q ^ sx) * 8];
    bf16x8 a1 = *(const bf16x8*)&la[(wm * 32 + 16 + l15) * 32 + (q ^ sx) * 8];
#pragma unroll
    for (int nt = 0; nt < 4; ++nt) {
      bf16x8 b = *(const bf16x8*)&lb[(wn * 64 + nt * 16 + l15) * 32 + (q ^ sx) * 8];
      acc[0][nt] = __builtin_amdgcn_mfma_f32_16x16x32_bf16(a0, b, acc[0][nt], 0, 0, 0);
      acc[1][nt] = __builtin_amdgcn_mfma_f32_16x16x32_bf16(a1, b, acc[1][nt], 0, 0, 0);
    }
    __builtin_amdgcn_sched_barrier(0);
    __builtin_amdgcn_s_barrier();
    __builtin_amdgcn_sched_barrier(0);
  }
  // packed C per block: 64x128 = 8192 floats; 16B/lane coalesced
  // slot = w*8 + mt*4 + nt; row = tile*64 + wm*32 + mt*16 + q*4 + i; col = wn*64 + nt*16 + l15
  float* ct = accBase + (size_t)blockIdx.y * SLICE_ELEMS + (size_t)blockIdx.x * 8192;
#pragma unroll
  for (int mt = 0; mt < 2; ++mt)
#pragma unroll
    for (int nt = 0; nt < 4; ++nt)
      *(f32x4*)&ct[((w * 8 + mt * 4 + nt) * 256) + (q * 16 + l15) * 4] = acc[mt][nt];
}

// ---------------- upsample GEMM reading W_up f32 directly ----------------
// out_partial[by] = f2bf(W_up)[64 rows x 512 k] @ X (XT [128 d][4096 k]).
// A: f32 reg-stage -> f2bf -> ds_write (identical rounding to the old cast path).

__global__ __launch_bounds__(256)
void up_agg_f32(const float* __restrict__ Wup, const unsigned short* __restrict__ BT,
                float* __restrict__ accBase) {
  __shared__ __align__(16) unsigned short smem[6144];    // A 4KB + B 8KB
  unsigned short* la = smem;
  unsigned short* lb = smem + 2048;
  const int t = threadIdx.x, w = t >> 6, lane = t & 63;
  const int q = lane >> 4, l15 = lane & 15;
  const int r0 = blockIdx.x * 64;                    // output rows
  const int k0 = blockIdx.y * 512;                   // k split
  const int arow = t >> 2, achk = t & 3;

  f32x4 acc[8];
#pragma unroll
  for (int b = 0; b < 8; ++b) acc[b] = (f32x4)0.f;

  for (int s = 0; s < 16; ++s) {
    int kb = k0 + s * 32;
    __syncthreads();
    gld16(&lb[t * 8],        &BT[(size_t)arow * N_NODES + kb + achk * 8]);
    gld16(&lb[2048 + t * 8], &BT[(size_t)(64 + arow) * N_NODES + kb + achk * 8]);
    const float* ap = &Wup[(size_t)(r0 + (t >> 2)) * N_NODES + kb + (t & 3) * 8];
    float4 v0 = *(const float4*)ap;
    float4 v1 = *(const float4*)(ap + 4);
    ushort4 o0, o1;
    o0.x = f2bf(v0.x); o0.y = f2bf(v0.y); o0.z = f2bf(v0.z); o0.w = f2bf(v0.w);
    o1.x = f2bf(v1.x); o1.y = f2bf(v1.y); o1.z = f2bf(v1.z); o1.w = f2bf(v1.w);
    *(ushort4*)&la[t * 8] = o0;
    *(ushort4*)&la[t * 8 + 4] = o1;
    __syncthreads();                                 // drains vm+lgkm: tiles visible

    bf16x8 a0 = *(const bf16x8*)&la[(w * 16 + l15) * 32 + q * 8];
#pragma unroll
    for (int nt = 0; nt < 8; ++nt) {
      bf16x8 b = *(const bf16x8*)&lb[(nt * 16 + l15) * 32 + q * 8];
      acc[nt] = __builtin_amdgcn_mfma_f32_16x16x32_bf16(a0, b, acc[nt], 0, 0, 0);
    }
  }
  float* ct = accBase + (size_t)blockIdx.y * SLICE_ELEMS + (size_t)blockIdx.x * 8192;
#pragma unroll
  for (int nt = 0; nt < 8; ++nt)
    *(f32x4*)&ct[((w * 8 + nt) * 256) + (q * 16 + l15) * 4] = acc[nt];
}

// sum packed (M64-tile) partials + epilogue -> bf16 row-major
// mode 0 (upsample layout): slot=w*8+nt, row=tile*64+w*16+q*4+i, col=nt*16+l15
// mode 1 (agg64 2x2 layout): slot=w*8+mt*4+nt, row=tile*64+(w&1)*32+mt*16+q*4+i,
//                            col=(w>>1)*64+nt*16+l15;  v=relu(rsqrt(deg)*s+bias_col)
__global__ void reduce64_kernel(const float* __restrict__ acc,
                                unsigned short* __restrict__ dst,
                                const float* __restrict__ bias_row,
                                const float* __restrict__ bias_col,
                                const float* __restrict__ deg, int mode, int nSlices) {
  int p = blockIdx.x * 256 + threadIdx.x;
  float s = 0.f;
  for (int sp = 0; sp < nSlices; ++sp) s += acc[(size_t)sp * SLICE_ELEMS + p];
  int tile = p >> 13, r = p & 8191;
  int grp = r >> 8;
  int r2 = r & 255;
  int i = r2 & 3, ql = r2 >> 2;
  int row, col;
  float v;
  if (mode == 0) {
    int w = grp >> 3, nt = grp & 7;
    row = tile * 64 + w * 16 + (ql >> 4) * 4 + i;
    col = nt * 16 + (ql & 15);
    v = s + bias_row[row];
  } else {
    int w = grp >> 3, mt = (grp >> 2) & 1, nt = grp & 3;
    row = tile * 64 + (w & 1) * 32 + mt * 16 + (ql >> 4) * 4 + i;
    col = (w >> 1) * 64 + nt * 16 + (ql & 15);
    float d = deg[row];
    float dv = d > 0.f ? rsqrtf(d) : 0.f;
    v = fmaxf(dv * s + bias_col[col], 0.f);
  }
  dst[(size_t)row * DIM + col] = f2bf(v);
}

// ---------------- TRIANGULAR rebuild: S = sigmoid(XA @ XB^T), K=128, S symmetric ----------
// (unchanged from R10; staging T2-swizzled; bitwise-identical mirrored tiles)

template <int MODE>
__global__ __launch_bounds__(256)
void rebuild_kernel(const unsigned short* __restrict__ XA,
                    const unsigned short* __restrict__ XB,
                    void* __restrict__ out, long p1 /*MODE0:row0, MODE1:ldo*/,
                    long col0, float* __restrict__ deg, int nB) {
  __shared__ __align__(16) unsigned short smem[34816];   // 69.6KB: staging 64KB / lC+lCt
  __shared__ float lcol[128];
  __shared__ float lrow[128];
  unsigned short* lA = smem;
  unsigned short* lB = smem + 16384;
  const int t = threadIdx.x, w = t >> 6, lane = t & 63;
  const int q = lane >> 4, l15 = lane & 15;
  const int sx = (l15 >> 1) & 3;                     // read-side swizzle key

  int rem = blockIdx.x, bi = 0;
  while (rem >= nB - bi) { rem -= nB - bi; ++bi; }
  const int bj = bi + rem;
  const int i0 = bi * 128, j0 = bj * 128;
  const bool offdiag = (bi != bj);

  const int srow = t >> 2;
  const int xchk = (t & 3) ^ ((t >> 3) & 3);         // source chunk (pre-swizzled)
#pragma unroll
  for (int kk = 0; kk < 4; ++kk)
#pragma unroll
    for (int h = 0; h < 2; ++h) {
      gld16(&lA[kk * 4096 + h * 2048 + t * 8],
            &XA[(size_t)(i0 + h * 64 + srow) * DIM + kk * 32 + xchk * 8]);
      gld16(&lB[kk * 4096 + h * 2048 + t * 8],
            &XB[(size_t)(j0 + h * 64 + srow) * DIM + kk * 32 + xchk * 8]);
    }
  if (MODE == 0 && t < 128) { lcol[t] = 0.f; lrow[t] = 0.f; }
  __syncthreads();

  f32x4 acc[2][8];
#pragma unroll
  for (int a = 0; a < 2; ++a)
#pragma unroll
    for (int b = 0; b < 8; ++b) acc[a][b] = (f32x4)0.f;

#pragma unroll
  for (int kk = 0; kk < 4; ++kk) {
    bf16x8 a0 = *(const bf16x8*)&lA[kk * 4096 + (w * 32 + l15) * 32 + ((q ^ sx)) * 8];
    bf16x8 a1 = *(const bf16x8*)&lA[kk * 4096 + (w * 32 + 16 + l15) * 32 + ((q ^ sx)) * 8];
#pragma unroll
    for (int nt = 0; nt < 8; ++nt) {
      bf16x8 b = *(const bf16x8*)&lB[kk * 4096 + (nt * 16 + l15) * 32 + ((q ^ sx)) * 8];
      acc[0][nt] = __builtin_amdgcn_mfma_f32_16x16x32_bf16(a0, b, acc[0][nt], 0, 0, 0);
      acc[1][nt] = __builtin_amdgcn_mfma_f32_16x16x32_bf16(a1, b, acc[1][nt], 0, 0, 0);
    }
  }
  __syncthreads();   // staging reads done; smem reusable

  if (MODE == 0) {
    unsigned short* lC  = smem;          // [128][136] bf16
    unsigned short* lCt = smem + 17408;  // [128][136] bf16 (transposed tile)
    float rs[2][4] = {{0.f, 0.f, 0.f, 0.f}, {0.f, 0.f, 0.f, 0.f}};
#pragma unroll
    for (int mt = 0; mt < 2; ++mt)
#pragma unroll
      for (int nt = 0; nt < 8; ++nt) {
        float cs = 0.f;
#pragma unroll
        for (int i = 0; i < 4; ++i) {
          float sv = sigmoidf_(acc[mt][nt][i]);
          cs += sv;
          unsigned short hb = f2bf(sv);
          int row = w * 32 + mt * 16 + q * 4 + i, colL = nt * 16 + l15;
          lC[row * 136 + colL] = hb;
          if (offdiag) { lCt[colL * 136 + row] = hb; rs[mt][i] += sv; }
        }
        cs += __shfl_xor(cs, 16);
        cs += __shfl_xor(cs, 32);
        if (lane < 16) atomicAdd(&lcol[nt * 16 + lane], cs);
      }
    if (offdiag) {
#pragma unroll
      for (int mt = 0; mt < 2; ++mt)
#pragma unroll
        for (int i = 0; i < 4; ++i) {
          float v = rs[mt][i];
          v += __shfl_xor(v, 1); v += __shfl_xor(v, 2);
          v += __shfl_xor(v, 4); v += __shfl_xor(v, 8);
          if (l15 == 0) atomicAdd(&lrow[w * 32 + mt * 16 + q * 4 + i], v);
        }
    }
    __syncthreads();
    unsigned short* og = (unsigned short*)out;
    {
      const long rowbase = p1 + i0, colbase = col0 + j0;
      const size_t tb = ((size_t)(rowbase >> 7) * 8 + (colbase >> 10)) * 131072;
      const int stb = (int)((colbase & 1023) >> 5);
#pragma unroll
      for (int cc = 0; cc < 8; ++cc) {
        int ch = t + cc * 256;
        int row = ch >> 4, c16 = ch & 15;
        *(bf16x8*)&og[tb + (size_t)(stb + (c16 >> 2)) * 4096 + row * 32 + (c16 & 3) * 8] =
            *(const bf16x8*)&lC[row * 136 + c16 * 8];
      }
    }
    if (offdiag) {
      const long rowbase = p1 + j0, colbase = col0 + i0;
      const size_t tb = ((size_t)(rowbase >> 7) * 8 + (colbase >> 10)) * 131072;
      const int stb = (int)((colbase & 1023) >> 5);
#pragma unroll
      for (int cc = 0; cc < 8; ++cc) {
        int ch = t + cc * 256;
        int row = ch >> 4, c16 = ch & 15;
        *(bf16x8*)&og[tb + (size_t)(stb + (c16 >> 2)) * 4096 + row * 32 + (c16 & 3) * 8] =
            *(const bf16x8*)&lCt[row * 136 + c16 * 8];
      }
    }
    if (t < 128) atomicAdd(&deg[col0 + j0 + t], lcol[t]);
    if (offdiag && t < 128) atomicAdd(&deg[col0 + i0 + t], lrow[t]);
  } else {
    float* og = (float*)out;
    float* lCf = (float*)smem;                   // [64][132] f32, stride keeps 16B align
#pragma unroll
    for (int mt = 0; mt < 2; ++mt)
#pragma unroll
      for (int nt = 0; nt < 8; ++nt)
#pragma unroll
        for (int i = 0; i < 4; ++i) acc[mt][nt][i] = sigmoidf_(acc[mt][nt][i]);
#pragma unroll
    for (int h2 = 0; h2 < 2; ++h2) {
      __syncthreads();
      if ((w >> 1) == h2) {
#pragma unroll
        for (int mt = 0; mt < 2; ++mt)
#pragma unroll
          for (int nt = 0; nt < 8; ++nt)
#pragma unroll
            for (int i = 0; i < 4; ++i)
              lCf[((w & 1) * 32 + mt * 16 + q * 4 + i) * 132 + nt * 16 + l15] =
                  acc[mt][nt][i];
      }
      __syncthreads();
#pragma unroll
      for (int j = 0; j < 8; ++j) {
        int ch = t + j * 256;
        int r64 = ch >> 5, c4 = (ch & 31) * 4;
        *(f32x4*)&og[(size_t)(i0 + h2 * 64 + r64) * p1 + j0 + c4] =
            *(const f32x4*)&lCf[r64 * 132 + c4];
      }
    }
    if (offdiag) {
#pragma unroll
      for (int h2 = 0; h2 < 2; ++h2) {
        __syncthreads();
#pragma unroll
        for (int mt = 0; mt < 2; ++mt)
#pragma unroll
          for (int nt = 0; nt < 8; ++nt)
            if ((nt >> 2) == h2) {
#pragma unroll
              for (int i = 0; i < 4; ++i)
                lCf[((nt & 3) * 16 + l15) * 132 + (w * 32 + mt * 16 + q * 4 + i)] =
                    acc[mt][nt][i];
            }
        __syncthreads();
#pragma unroll
        for (int j = 0; j < 8; ++j) {
          int ch = t + j * 256;
          int r64 = ch >> 5, c4 = (ch & 31) * 4;
          *(f32x4*)&og[(size_t)(j0 + h2 * 64 + r64) * p1 + i0 + c4] =
              *(const f32x4*)&lCf[r64 * 132 + c4];
        }
      }
    }
  }
}

// ---------------- Z^T = (rsqrt(deg) ⊙ (Xu @ W)) transposed, [128][8192] ----------------
// Staging T2-swizzled. zbuf (optional): zero next-gen deg buffer (folds a memset launch).

__global__ __launch_bounds__(256)
void yz_kernel(const unsigned short* __restrict__ Xu, const unsigned short* __restrict__ WT,
               const float* __restrict__ deg, unsigned short* __restrict__ ZT, int ldz,
               float* __restrict__ zbuf) {
  __shared__ __align__(16) unsigned short smem[32768];
  unsigned short* lA = smem;
  unsigned short* lB = smem + 16384;
  const int t = threadIdx.x, w = t >> 6, lane = t & 63;
  const int q = lane >> 4, l15 = lane & 15;
  const int sx = (l15 >> 1) & 3;
  const int r0 = blockIdx.x * 128;
  if (zbuf) {
    int gid = blockIdx.x * 256 + t;
    if (gid < M_NODES) zbuf[gid] = 0.f;
  }
  const int srow = t >> 2;
  const int xchk = (t & 3) ^ ((t >> 3) & 3);
#pragma unroll
  for (int kk = 0; kk < 4; ++kk)
#pragma unroll
    for (int h = 0; h < 2; ++h) {
      gld16(&lA[kk * 4096 + h * 2048 + t * 8],
            &Xu[(size_t)(r0 + h * 64 + srow) * DIM + kk * 32 + xchk * 8]);
      gld16(&lB[kk * 4096 + h * 2048 + t * 8],
            &WT[(size_t)(h * 64 + srow) * DIM + kk * 32 + xchk * 8]);
    }
  __syncthreads();

  f32x4 acc[2][8];
#pragma unroll
  for (int a = 0; a < 2; ++a)
#pragma unroll
    for (int b = 0; b < 8; ++b) acc[a][b] = (f32x4)0.f;

#pragma unroll
  for (int kk = 0; kk < 4; ++kk) {
    bf16x8 a0 = *(const bf16x8*)&lA[kk * 4096 + (w * 32 + l15) * 32 + (q ^ sx) * 8];
    bf16x8 a1 = *(const bf16x8*)&lA[kk * 4096 + (w * 32 + 16 + l15) * 32 + (q ^ sx) * 8];
#pragma unroll
    for (int nt = 0; nt < 8; ++nt) {
      bf16x8 b = *(const bf16x8*)&lB[kk * 4096 + (nt * 16 + l15) * 32 + (q ^ sx) * 8];
      acc[0][nt] = __builtin_amdgcn_mfma_f32_16x16x32_bf16(a0, b, acc[0][nt], 0, 0, 0);
      acc[1][nt] = __builtin_amdgcn_mfma_f32_16x16x32_bf16(a1, b, acc[1][nt], 0, 0, 0);
    }
  }
  __syncthreads();
  unsigned short* lT = smem;   // [c 128][r 136]
#pragma unroll
  for (int mt = 0; mt < 2; ++mt)
#pragma unroll
    for (int i = 0; i < 4; ++i) {
      int r = w * 32 + mt * 16 + q * 4 + i;
      float d = deg[r0 + r];
      float dv = d > 0.f ? rsqrtf(d) : 0.f;
#pragma unroll
      for (int nt = 0; nt < 8; ++nt)
        lT[(nt * 16 + l15) * 136 + r] = f2bf(dv * acc[mt][nt][i]);
    }
  __syncthreads();
#pragma unroll
  for (int cc = 0; cc < 8; ++cc) {
    int ch = t + cc * 256;
    int c = ch >> 4, c16 = ch & 15;
    *(bf16x8*)&ZT[(size_t)c * ldz + r0 + c16 * 8] = *(const bf16x8*)&lT[c * 136 + c16 * 8];
  }
}

// ---------------- driver ----------------

extern "C" void kernel_launch(void* const* d_in, const int* in_sizes, int n_in,
                              void* d_out, int out_size, void* d_ws, size_t ws_size,
                              hipStream_t stream) {
  (void)in_sizes; (void)n_in; (void)out_size;
  const float* X   = (const float*)d_in[0];
  const float* A   = (const float*)d_in[1];
  const float* Wup = (const float*)d_in[2];
  const float* bup = (const float*)d_in[3];
  const float* W1  = (const float*)d_in[4];
  const float* b1  = (const float*)d_in[5];
  const float* W2  = (const float*)d_in[6];
  const float* b2  = (const float*)d_in[7];

  const size_t ADJ_BYTES = (size_t)M_NODES * M_NODES * 2;
  char* ws = (char*)d_ws;
  size_t off = 0;
  auto alloc = [&](size_t bytes) {
    char* p = ws + off;
    off += (bytes + 255) & ~(size_t)255;
    return p;
  };
  float*          accb    = (float*)alloc(8 * SLICE_ELEMS * 4);                  // 33.5 MB
  unsigned short* Xu      = (unsigned short*)alloc((size_t)M_NODES * DIM * 2);
  unsigned short* ZT      = (unsigned short*)alloc((size_t)DIM * M_NODES * 2);
  unsigned short* XT      = (unsigned short*)alloc((size_t)DIM * N_NODES * 2);
  unsigned short* W1T     = (unsigned short*)alloc(DIM * DIM * 2);
  unsigned short* W2T     = (unsigned short*)alloc(DIM * DIM * 2);
  float*          colsumA = (float*)alloc(N_NODES * 4);
  float*          degA    = (float*)alloc(M_NODES * 4);
  float*          degB    = (float*)alloc(M_NODES * 4);

  unsigned short* Adj;
  if (ws_size >= off + ADJ_BYTES) Adj = (unsigned short*)(ws + off);
  else                            Adj = (unsigned short*)d_out;  // Adj dead before final write

  unsigned short* XuNew = Xu + (size_t)N_NODES * DIM;

  cast_x_kernel<<<N_NODES * DIM / 256, 256, 0, stream>>>(X, Xu, XT, colsumA);
  cast_wt2_kernel<<<128, 256, 0, stream>>>(W1, W2, W1T, W2T);

  // new = W_up @ X (+ b_up): K=4096, direct f32 A-read, 8 splits x 16 stages
  up_agg_f32<<<dim3(N_NODES / 64, 8), 256, 0, stream>>>(Wup, XT, accb);
  reduce64_kernel<<<N_NODES * DIM / 256, 256, 0, stream>>>(
      accb, XuNew, bup, nullptr, nullptr, 0, 8);

  // Adj0 blocks [[A,A],[A,.]] tiled + colsum; deg; S0 = sigmoid(new@new^T) into (4096+,4096+)
  cast_a_kernel<<<dim3(N_NODES / 256, N_NODES / 128), 256, 0, stream>>>(A, Adj, colsumA);
  init_deg_kernel<<<M_NODES / 256, 256, 0, stream>>>(colsumA, degA);
  rebuild_kernel<0><<<32 * 33 / 2, 256, 0, stream>>>(
      XuNew, XuNew, Adj, N_NODES, N_NODES, degA, 32);

  float* degCur = degA;   // deg for conv1 (prev generation's mid-loop Adj)
  float* degMid = degB;   // deg for this generation's mid-loop Adj
  for (int it = 0; it < 3; ++it) {
    // conv1 (Adj = prev mid-loop matrix; iter0: Adj0). yz also zeroes degMid.
    yz_kernel<<<M_NODES / 128, 256, 0, stream>>>(Xu, W1T, degCur, ZT, M_NODES, degMid);
    agg64_kernel<<<dim3(M_NODES / 64, 4), 256, 0, stream>>>(Adj, ZT, M_NODES, accb, 64);
    reduce64_kernel<<<M_NODES * DIM / 256, 256, 0, stream>>>(
        accb, Xu, nullptr, b1, degCur, 1, 4);
    // mid-loop Adj rebuild (triangular) + deg into degMid
    rebuild_kernel<0><<<64 * 65 / 2, 256, 0, stream>>>(
        Xu, Xu, Adj, 0, 0, degMid, 64);
    // conv2 (Adj = mid-loop matrix)
    yz_kernel<<<M_NODES / 128, 256, 0, stream>>>(Xu, W2T, degMid, ZT, M_NODES, nullptr);
    agg64_kernel<<<dim3(M_NODES / 64, 4), 256, 0, stream>>>(Adj, ZT, M_NODES, accb, 64);
    reduce64_kernel<<<M_NODES * DIM / 256, 256, 0, stream>>>(
        accb, Xu, nullptr, b2, degMid, 1, 4);
    if (it == 2)
      rebuild_kernel<1><<<64 * 65 / 2, 256, 0, stream>>>(
          Xu, Xu, d_out, M_NODES, 0, nullptr, 64);
    float* tmp = degCur; degCur = degMid; degMid = tmp;
  }
}